// Round 2
// baseline (227.211 us; speedup 1.0000x reference)
//
#include <hip/hip_runtime.h>
#include <math.h>

// ---------------------------------------------------------------- types
typedef __bf16 bf16_t;
typedef bf16_t bf16x8 __attribute__((ext_vector_type(8)));
typedef float f32x4 __attribute__((ext_vector_type(4)));

#define S_LEN 2048
#define NHEAD 16
#define DHEAD 64
#define DMODEL 1024
#define BATCH 2

__device__ __forceinline__ float bf2f(unsigned short u) {
    unsigned int x = ((unsigned int)u) << 16;
    return __builtin_bit_cast(float, x);
}
__device__ __forceinline__ unsigned short f2bf(float f) {
    unsigned int x = __builtin_bit_cast(unsigned int, f);
    x += 0x7fffu + ((x >> 16) & 1u);          // RNE
    return (unsigned short)(x >> 16);
}

// async global->LDS, 16B per lane. LDS dest = wave-uniform base + lane*16.
__device__ __forceinline__ void glds16(const void* g, void* l) {
    __builtin_amdgcn_global_load_lds(
        (__attribute__((address_space(1))) void*)g,
        (__attribute__((address_space(3))) void*)l,
        16, 0, 0);
}

#define SCALE2 0.1803368801f   // 1/sqrt(64) * log2(e), folded into Q at qkv epilogue

// ---------------------------------------------------------------- fp32 -> bf16 convert
__global__ __launch_bounds__(256) void cvt_kernel(
    const float* __restrict__ x,  const float* __restrict__ wq,
    const float* __restrict__ wk, const float* __restrict__ wv,
    const float* __restrict__ wo,
    unsigned short* __restrict__ xb,  unsigned short* __restrict__ wqb,
    unsigned short* __restrict__ wkb, unsigned short* __restrict__ wvb,
    unsigned short* __restrict__ wob)
{
    const int y = blockIdx.y;
    const float* s = (y == 0) ? x : (y == 1) ? wq : (y == 2) ? wk : (y == 3) ? wv : wo;
    unsigned short* d = (y == 0) ? xb : (y == 1) ? wqb : (y == 2) ? wkb : (y == 3) ? wvb : wob;
    const int n4 = (y == 0) ? (1 << 20) : (1 << 18);
    const int i = blockIdx.x * 256 + threadIdx.x;
    if (i < n4) {
        float4 v = ((const float4*)s)[i];
        ushort4 o;
        o.x = f2bf(v.x); o.y = f2bf(v.y); o.z = f2bf(v.z); o.w = f2bf(v.w);
        ((ushort4*)d)[i] = o;
    }
}

// ---------------------------------------------------------------- RoPE cos/sin table
__global__ __launch_bounds__(256) void rope_table_kernel(float2* __restrict__ tab)
{
    const int gid = blockIdx.x * 256 + threadIdx.x;   // 65536
    const int s = gid >> 5, d = gid & 31;
    const float freq = exp2f(-0.4152410119f * (float)d);
    const float ang = (float)s * freq;
    tab[gid] = make_float2(cosf(ang), sinf(ang));
}

// ---------------------------------------------------------------- fused QKV GEMM
// xb[M][1024] bf16, W*b[1024][1024] bf16. which = blockIdx.x>>3.
// Q: RoPE + SCALE2 folded, out [B,S,1024] bf16.  K: RoPE, same layout.
// V: out transposed VT[B,H,Dh,S] bf16.
__global__ __launch_bounds__(256, 2) void qkv_gemm_kernel(
    const unsigned short* __restrict__ xb,
    const unsigned short* __restrict__ wqb, const unsigned short* __restrict__ wkb,
    const unsigned short* __restrict__ wvb,
    const float* __restrict__ bq, const float* __restrict__ bk, const float* __restrict__ bv,
    const float2* __restrict__ tab,
    unsigned short* __restrict__ Qr, unsigned short* __restrict__ Kr,
    unsigned short* __restrict__ VT)
{
    __shared__ __align__(16) unsigned short As[128 * 32];
    __shared__ __align__(16) unsigned short Bs[128 * 32];

    const int which = blockIdx.x >> 3;
    const int bn = (blockIdx.x & 7) * 128;
    const int bm = blockIdx.y * 128;
    const unsigned short* W = (which == 0) ? wqb : (which == 1) ? wkb : wvb;
    const float* bias       = (which == 0) ? bq  : (which == 1) ? bk  : bv;

    const int tid  = threadIdx.x;
    const int lane = tid & 63;
    const int w    = tid >> 6;
    const int quad = lane >> 4;
    const int l16  = lane & 15;
    const int wm   = (w >> 1) * 64;
    const int wn   = (w & 1) * 64;

    f32x4 acc[4][4];
#pragma unroll
    for (int i = 0; i < 4; ++i)
#pragma unroll
        for (int j = 0; j < 4; ++j)
            acc[i][j] = f32x4{0.f, 0.f, 0.f, 0.f};

    const int r0 = tid >> 2, c0 = (tid & 3) * 8;
    const unsigned short* ga0 = xb + (size_t)(bm + r0) * DMODEL + c0;
    const unsigned short* ga1 = ga0 + (size_t)64 * DMODEL;
    const unsigned short* gb0 = W  + (size_t)(bn + r0) * DMODEL + c0;
    const unsigned short* gb1 = gb0 + (size_t)64 * DMODEL;
    unsigned short* la0 = As + tid * 8;
    unsigned short* la1 = As + (tid + 256) * 8;
    unsigned short* lb0 = Bs + tid * 8;
    unsigned short* lb1 = Bs + (tid + 256) * 8;

    for (int k0 = 0; k0 < DMODEL; k0 += 32) {
        glds16(ga0 + k0, la0);
        glds16(ga1 + k0, la1);
        glds16(gb0 + k0, lb0);
        glds16(gb1 + k0, lb1);
        __syncthreads();

        bf16x8 aF[4], bF[4];
#pragma unroll
        for (int t = 0; t < 4; ++t) {
            aF[t] = *(const bf16x8*)(&As[(wm + t * 16 + l16) * 32 + quad * 8]);
            bF[t] = *(const bf16x8*)(&Bs[(wn + t * 16 + l16) * 32 + quad * 8]);
        }
#pragma unroll
        for (int mt = 0; mt < 4; ++mt)
#pragma unroll
            for (int nt = 0; nt < 4; ++nt)
                acc[mt][nt] = __builtin_amdgcn_mfma_f32_16x16x32_bf16(
                    aF[mt], bF[nt], acc[mt][nt], 0, 0, 0);
        __syncthreads();
    }

    // ---- epilogue
    if (which < 2) {
        unsigned short* Y = (which == 0) ? Qr : Kr;
        const float qscale = (which == 0) ? SCALE2 : 1.0f;
#pragma unroll
        for (int mt = 0; mt < 4; ++mt) {
            const int row0 = bm + wm + mt * 16 + quad * 4;
#pragma unroll
            for (int nt = 0; nt < 2; ++nt) {
                const int d   = nt * 16 + l16;       // 0..31 within head
                const int col = bn + wn + nt * 16 + l16;
                const float b1 = bias[col];
                const float b2 = bias[col + 32];
#pragma unroll
                for (int r = 0; r < 4; ++r) {
                    const int row = row0 + r;
                    const int s = row & (S_LEN - 1);
                    const float2 cs = tab[s * 32 + d];
                    const float x1 = acc[mt][nt][r] + b1;
                    const float x2 = acc[mt][nt + 2][r] + b2;
                    Y[(size_t)row * DMODEL + col]      = f2bf((x1 * cs.x - x2 * cs.y) * qscale);
                    Y[(size_t)row * DMODEL + col + 32] = f2bf((x2 * cs.x + x1 * cs.y) * qscale);
                }
            }
        }
    } else {
#pragma unroll
        for (int mt = 0; mt < 4; ++mt) {
            const int row0 = bm + wm + mt * 16 + quad * 4;
            const int bb = row0 >> 11, s0 = row0 & (S_LEN - 1);
            const int h = (bn + wn) >> 6;
#pragma unroll
            for (int nt = 0; nt < 4; ++nt) {
                const int d = nt * 16 + l16;
                const float bv2 = bias[bn + wn + nt * 16 + l16];
                unsigned short pk[4];
#pragma unroll
                for (int r = 0; r < 4; ++r)
                    pk[r] = f2bf(acc[mt][nt][r] + bv2);
                *(uint2*)(&VT[((size_t)(bb * NHEAD + h) * DHEAD + d) * S_LEN + s0]) =
                    *(const uint2*)pk;
            }
        }
    }
}

// ---------------------------------------------------------------- attention
// Round-12: causal flash-decoding split. Each (b,h,qt) row-block is split
// into chunks of <=4 k-tiles -> 1280 blocks (5/CU), work in {1..4} tiles.
// Rationale (rocprof): Occ 24.4% == predicted intra-pair idle of the static
// 2-blocks/CU complementary pairing; finer work units let the scheduler
// backfill. The no-max softmax makes partials trivially additive: each
// chunk stores unnormalized o (f32) and l; a combine pass sums and
// normalizes. Inner math identical to round-11 (verified).
#define VSTR 136   // Pb row stride (shorts): 128 + 8 pad
#define CHUNK 4    // k-tiles per chunk

__global__ __launch_bounds__(512, 4) void attn_kernel(
    const unsigned short* __restrict__ Q, const unsigned short* __restrict__ K,
    const unsigned short* __restrict__ VT,
    float* __restrict__ Opart, float* __restrict__ Lpart)
{
    // ---- block -> (b, h, qt, cs). cid enumerates (qt, cs) canonically;
    // dispatch reversed so heavy chunks (4 tiles) launch first.
    const int j   = blockIdx.x;          // 0..1279
    const int bh  = j / 40;
    const int cid = 39 - (j - bh * 40);  // canonical chunk id 0..39
    const int b   = bh >> 4, h = bh & 15;
    int g, rel;
    if (cid < 4)       { g = 0; rel = cid; }
    else if (cid < 12) { g = 1; rel = cid - 4; }
    else if (cid < 24) { g = 2; rel = cid - 12; }
    else               { g = 3; rel = cid - 24; }
    const int qt = 4 * g + rel / (g + 1);
    const int cs = rel - (rel / (g + 1)) * (g + 1);
    const int slot = bh * 40 + cid;

    const int tid  = threadIdx.x;
    const int w    = tid >> 6;          // 0..7
    const int lane = tid & 63;
    const int quad = lane >> 4;
    const int l16  = lane & 15;

    __shared__ __align__(16) unsigned short Ks[128 * 64];      // [kpos][dh]  swizzled
    __shared__ __align__(16) unsigned short Vt[64 * 128];      // [dh][kpos] swizzled
    __shared__ __align__(16) unsigned short Pb[8 * 16 * VSTR]; // per-wave [q][kpos]

    const int q0 = qt * 128;
    const unsigned short* Qb = Q  + (size_t)b * S_LEN * DMODEL + h * DHEAD;
    const unsigned short* Kb = K  + (size_t)b * S_LEN * DMODEL + h * DHEAD;
    const unsigned short* Vh = VT + ((size_t)(b * NHEAD + h)) * DHEAD * S_LEN;

    // Q fragments: rows q0 + w*16 + l16
    const int qrow = q0 + w * 16 + l16;
    const bf16x8 qf0 = *(const bf16x8*)(Qb + (size_t)qrow * DMODEL + quad * 8);
    const bf16x8 qf1 = *(const bf16x8*)(Qb + (size_t)qrow * DMODEL + 32 + quad * 8);

    f32x4 o[4];
#pragma unroll
    for (int i = 0; i < 4; ++i) o[i] = f32x4{0.f, 0.f, 0.f, 0.f};
    float l_i[4] = {0.f, 0.f, 0.f, 0.f};

    const int k0t  = cs * CHUNK;
    const int kend = (k0t + CHUNK < qt + 1) ? (k0t + CHUNK) : (qt + 1);
    unsigned short* Pw = &Pb[w * 16 * VSTR];

    for (int kt = k0t; kt < kend; ++kt) {
        // ---- async stage K (128x64) and V^T (64x128), XOR-swizzled source
#pragma unroll
        for (int i = 0; i < 2; ++i) {
            const int ck = tid + i * 512;
            const int krow = ck >> 3, kc = ck & 7;
            glds16(Kb + (size_t)(kt * 128 + krow) * DMODEL + ((kc ^ (krow & 7)) * 8),
                   Ks + ck * 8);
            const int vrow = ck >> 4, vc = ck & 15;
            glds16(Vh + (size_t)vrow * S_LEN + kt * 128 + ((vc ^ (vrow & 15)) * 8),
                   Vt + ck * 8);
        }
        __syncthreads();   // glds drained (vmcnt) + all waves here

        const bool diag = (kt == qt);
        // Wave w's rows only see kpos <= q0 + w*16 + 15 on the diagonal tile;
        // round up to a 32-kpos block so masked entries are exact zeros.
        const int ntmax = diag ? ((w & ~1) + 2) : 8;
        const int cmax  = ntmax >> 1;

        // ---- scores: 16 q-rows x (ntmax*16) kpos
        f32x4 sc[8];
#pragma unroll
        for (int nt = 0; nt < 8; ++nt) {
            if (nt >= ntmax) break;
            const int row = nt * 16 + l16;
            const bf16x8 kf0 = *(const bf16x8*)(&Ks[row * 64 + ((quad ^ (l16 & 7)) * 8)]);
            const bf16x8 kf1 = *(const bf16x8*)(&Ks[row * 64 + (((4 + quad) ^ (l16 & 7)) * 8)]);
            f32x4 a = f32x4{0.f, 0.f, 0.f, 0.f};
            a = __builtin_amdgcn_mfma_f32_16x16x32_bf16(qf0, kf0, a, 0, 0, 0);
            a = __builtin_amdgcn_mfma_f32_16x16x32_bf16(qf1, kf1, a, 0, 0, 0);
            sc[nt] = a;
        }

        if (diag) {   // triangular mask within the diagonal tile
            const int qpos0 = q0 + w * 16 + quad * 4;
#pragma unroll
            for (int nt = 0; nt < 8; ++nt) {
                if (nt >= ntmax) break;
                const int kpos = kt * 128 + nt * 16 + l16;
#pragma unroll
                for (int r = 0; r < 4; ++r)
                    if (kpos > qpos0 + r) sc[nt][r] = -INFINITY;
            }
        }

        // ---- exp2 + unnormalized accumulate
#pragma unroll
        for (int nt = 0; nt < 8; ++nt) {
            if (nt >= ntmax) break;
#pragma unroll
            for (int r = 0; r < 4; ++r) {
                const float e = exp2f(sc[nt][r]);
                sc[nt][r] = e;
                l_i[r] += e;
            }
        }

        // ---- P: C-layout -> per-wave LDS -> A-layout (no barrier)
#pragma unroll
        for (int nt = 0; nt < 8; ++nt) {
            if (nt >= ntmax) break;
#pragma unroll
            for (int r = 0; r < 4; ++r)
                Pw[(quad * 4 + r) * VSTR + nt * 16 + l16] = f2bf(sc[nt][r]);
        }

        bf16x8 pA[4];
#pragma unroll
        for (int c = 0; c < 4; ++c) {
            if (c >= cmax) break;
            pA[c] = *(const bf16x8*)(&Pw[l16 * VSTR + c * 32 + quad * 8]);
        }
#pragma unroll
        for (int nt = 0; nt < 4; ++nt) {
            const int row = nt * 16 + l16;
#pragma unroll
            for (int c = 0; c < 4; ++c) {
                if (c >= cmax) break;
                const bf16x8 vF = *(const bf16x8*)(&Vt[row * 128 + (((c * 4 + quad) ^ l16) * 8)]);
                o[nt] = __builtin_amdgcn_mfma_f32_16x16x32_bf16(pA[c], vF, o[nt], 0, 0, 0);
            }
        }
        __syncthreads();   // all readers done before next tile's glds overwrites
    }

    // ---- epilogue: store unnormalized partials (f32) + per-row l
    float* Op = Opart + (size_t)slot * (128 * 64);
    float* Lp = Lpart + slot * 128;
    const int row0 = w * 16 + quad * 4;   // row within the 128-row tile
#pragma unroll
    for (int r = 0; r < 4; ++r) {
        float rs = l_i[r];
#pragma unroll
        for (int msk = 1; msk < 16; msk <<= 1)
            rs += __shfl_xor(rs, msk);
        if (l16 == 0) Lp[row0 + r] = rs;
    }
#pragma unroll
    for (int nt = 0; nt < 4; ++nt)
#pragma unroll
        for (int r = 0; r < 4; ++r)
            Op[(row0 + r) * 64 + nt * 16 + l16] = o[nt][r];
}

// ---------------------------------------------------------------- attention combine
// Sum <=4 chunk partials (trivially additive: no-max softmax), normalize,
// emit bf16 AO. ~50 MB traffic, mostly L2/L3 resident.
__global__ __launch_bounds__(256) void attn_combine_kernel(
    const float* __restrict__ Opart, const float* __restrict__ Lpart,
    unsigned short* __restrict__ AO)
{
    const int bid = blockIdx.x;           // 512 = B * NHEAD * 16
    const int b = bid >> 8, rem = bid & 255, h = rem >> 4, qt = rem & 15;
    const int g = qt >> 2, rr = qt & 3;
    const int off = (g + 1) * (2 * g + rr);
    const int nc  = g + 1;
    const int s0  = (b * NHEAD + h) * 40 + off;
    const int t   = threadIdx.x;

#pragma unroll
    for (int jj = 0; jj < 8; ++jj) {
        const int idx = jj * 1024 + t * 4;    // 0..8191, float4-aligned
        const int row = idx >> 6, dh = idx & 63;
        float4 acc = make_float4(0.f, 0.f, 0.f, 0.f);
        float l = 0.f;
        for (int c = 0; c < nc; ++c) {
            const float4 p = *(const float4*)(Opart + (size_t)(s0 + c) * 8192 + idx);
            acc.x += p.x; acc.y += p.y; acc.z += p.z; acc.w += p.w;
            l += Lpart[(s0 + c) * 128 + row];
        }
        const float linv = 1.0f / l;
        ushort4 o;
        o.x = f2bf(acc.x * linv); o.y = f2bf(acc.y * linv);
        o.z = f2bf(acc.z * linv); o.w = f2bf(acc.w * linv);
        *(ushort4*)(AO + ((size_t)(b * S_LEN + qt * 128 + row)) * DMODEL + h * DHEAD + dh) = o;
    }
}

// ---------------------------------------------------------------- out-proj GEMM (bf16 x bf16 -> fp32)
__global__ __launch_bounds__(256, 2) void outproj_kernel(
    const unsigned short* __restrict__ A, const unsigned short* __restrict__ W,
    const float* __restrict__ bias, float* __restrict__ C)
{
    __shared__ __align__(16) unsigned short As[64 * 32];
    __shared__ __align__(16) unsigned short Bs[128 * 32];

    const int tid  = threadIdx.x;
    const int lane = tid & 63;
    const int w    = tid >> 6;
    const int quad = lane >> 4;
    const int l16  = lane & 15;
    const int wm   = (w >> 1) * 32;
    const int wn   = (w & 1) * 64;
    const int bm   = blockIdx.y * 64;
    const int bn   = blockIdx.x * 128;

    f32x4 acc[2][4];
#pragma unroll
    for (int i = 0; i < 2; ++i)
#pragma unroll
        for (int j = 0; j < 4; ++j)
            acc[i][j] = f32x4{0.f, 0.f, 0.f, 0.f};

    const int r0 = tid >> 2, c0 = (tid & 3) * 8;
    const unsigned short* ga  = A + (size_t)(bm + r0) * DMODEL + c0;
    const unsigned short* gb0 = W + (size_t)(bn + r0) * DMODEL + c0;
    const unsigned short* gb1 = gb0 + (size_t)64 * DMODEL;
    unsigned short* la  = As + tid * 8;
    unsigned short* lb0 = Bs + tid * 8;
    unsigned short* lb1 = Bs + (tid + 256) * 8;

    for (int k0 = 0; k0 < DMODEL; k0 += 32) {
        glds16(ga + k0, la);
        glds16(gb0 + k0, lb0);
        glds16(gb1 + k0, lb1);
        __syncthreads();

        bf16x8 aF[2], bF[4];
#pragma unroll
        for (int t = 0; t < 2; ++t)
            aF[t] = *(const bf16x8*)(&As[(wm + t * 16 + l16) * 32 + quad * 8]);
#pragma unroll
        for (int t = 0; t < 4; ++t)
            bF[t] = *(const bf16x8*)(&Bs[(wn + t * 16 + l16) * 32 + quad * 8]);
#pragma unroll
        for (int mt = 0; mt < 2; ++mt)
#pragma unroll
            for (int nt = 0; nt < 4; ++nt)
                acc[mt][nt] = __builtin_amdgcn_mfma_f32_16x16x32_bf16(
                    aF[mt], bF[nt], acc[mt][nt], 0, 0, 0);
        __syncthreads();
    }

#pragma unroll
    for (int mt = 0; mt < 2; ++mt) {
        const int row0 = bm + wm + mt * 16 + quad * 4;
#pragma unroll
        for (int nt = 0; nt < 4; ++nt) {
            const int col = bn + wn + nt * 16 + l16;
            const float bv = bias[col];
#pragma unroll
            for (int r = 0; r < 4; ++r)
                C[(size_t)(row0 + r) * DMODEL + col] = acc[mt][nt][r] + bv;
        }
    }
}

// ---------------------------------------------------------------- launch
extern "C" void kernel_launch(void* const* d_in, const int* in_sizes, int n_in,
                              void* d_out, int out_size, void* d_ws, size_t ws_size,
                              hipStream_t stream) {
    const float* x  = (const float*)d_in[0];
    const float* Wq = (const float*)d_in[1];
    const float* bq = (const float*)d_in[2];
    const float* Wk = (const float*)d_in[3];
    const float* bk = (const float*)d_in[4];
    const float* Wv = (const float*)d_in[5];
    const float* bv = (const float*)d_in[6];
    const float* Wo = (const float*)d_in[7];
    const float* bo = (const float*)d_in[8];
    float* out = (float*)d_out;

    char* ws = (char*)d_ws;
    const size_t MB = 1 << 20;
    unsigned short* xb  = (unsigned short*)(ws);            //  8 MB
    unsigned short* wqb = (unsigned short*)(ws + 8  * MB);  //  2 MB each
    unsigned short* wkb = (unsigned short*)(ws + 10 * MB);
    unsigned short* wvb = (unsigned short*)(ws + 12 * MB);
    unsigned short* wob = (unsigned short*)(ws + 14 * MB);
    float2*         tab = (float2*)       (ws + 16 * MB);   // 512 KB
    unsigned short* Qr  = (unsigned short*)(ws + 17 * MB);  //  8 MB
    unsigned short* Kr  = (unsigned short*)(ws + 25 * MB);
    unsigned short* VT  = (unsigned short*)(ws + 33 * MB);
    unsigned short* AO  = (unsigned short*)(ws + 41 * MB);  //  8 MB
    float*          Opart = (float*)      (ws + 49 * MB);   // 1280*8192*4 = 40 MB
    float*          Lpart = (float*)      (ws + 90 * MB);   // 1280*128*4  = 640 KB

    const int M = BATCH * S_LEN;   // 4096

    cvt_kernel<<<dim3(4096, 5), 256, 0, stream>>>(
        x, Wq, Wk, Wv, Wo, xb, wqb, wkb, wvb, wob);

    rope_table_kernel<<<256, 256, 0, stream>>>(tab);

    qkv_gemm_kernel<<<dim3(24, M / 128), 256, 0, stream>>>(
        xb, wqb, wkb, wvb, bq, bk, bv, tab, Qr, Kr, VT);

    attn_kernel<<<dim3(1280), 512, 0, stream>>>(Qr, Kr, VT, Opart, Lpart);

    attn_combine_kernel<<<dim3(512), 256, 0, stream>>>(Opart, Lpart, AO);

    outproj_kernel<<<dim3(DMODEL / 128, M / 64), 256, 0, stream>>>(AO, wob, bo, out);
}

// Round 3
// 206.171 us; speedup vs baseline: 1.1021x; 1.1021x over previous
//
#include <hip/hip_runtime.h>
#include <math.h>

// ---------------------------------------------------------------- types
typedef __bf16 bf16_t;
typedef bf16_t bf16x8 __attribute__((ext_vector_type(8)));
typedef float f32x4 __attribute__((ext_vector_type(4)));

#define S_LEN 2048
#define NHEAD 16
#define DHEAD 64
#define DMODEL 1024
#define BATCH 2

__device__ __forceinline__ float bf2f(unsigned short u) {
    unsigned int x = ((unsigned int)u) << 16;
    return __builtin_bit_cast(float, x);
}
__device__ __forceinline__ unsigned short f2bf(float f) {
    unsigned int x = __builtin_bit_cast(unsigned int, f);
    x += 0x7fffu + ((x >> 16) & 1u);          // RNE
    return (unsigned short)(x >> 16);
}

// async global->LDS, 16B per lane. LDS dest = wave-uniform base + lane*16.
__device__ __forceinline__ void glds16(const void* g, void* l) {
    __builtin_amdgcn_global_load_lds(
        (__attribute__((address_space(1))) void*)g,
        (__attribute__((address_space(3))) void*)l,
        16, 0, 0);
}

#define SCALE2 0.1803368801f   // 1/sqrt(64) * log2(e), folded into Q at qkv epilogue

// ---------------------------------------------------------------- fp32 -> bf16 convert
__global__ __launch_bounds__(256) void cvt_kernel(
    const float* __restrict__ x,  const float* __restrict__ wq,
    const float* __restrict__ wk, const float* __restrict__ wv,
    const float* __restrict__ wo,
    unsigned short* __restrict__ xb,  unsigned short* __restrict__ wqb,
    unsigned short* __restrict__ wkb, unsigned short* __restrict__ wvb,
    unsigned short* __restrict__ wob)
{
    const int y = blockIdx.y;
    const float* s = (y == 0) ? x : (y == 1) ? wq : (y == 2) ? wk : (y == 3) ? wv : wo;
    unsigned short* d = (y == 0) ? xb : (y == 1) ? wqb : (y == 2) ? wkb : (y == 3) ? wvb : wob;
    const int n4 = (y == 0) ? (1 << 20) : (1 << 18);
    const int i = blockIdx.x * 256 + threadIdx.x;
    if (i < n4) {
        float4 v = ((const float4*)s)[i];
        ushort4 o;
        o.x = f2bf(v.x); o.y = f2bf(v.y); o.z = f2bf(v.z); o.w = f2bf(v.w);
        ((ushort4*)d)[i] = o;
    }
}

// ---------------------------------------------------------------- RoPE cos/sin table
__global__ __launch_bounds__(256) void rope_table_kernel(float2* __restrict__ tab)
{
    const int gid = blockIdx.x * 256 + threadIdx.x;   // 65536
    const int s = gid >> 5, d = gid & 31;
    const float freq = exp2f(-0.4152410119f * (float)d);
    const float ang = (float)s * freq;
    tab[gid] = make_float2(cosf(ang), sinf(ang));
}

// ---------------------------------------------------------------- fused QKV GEMM
__global__ __launch_bounds__(256, 2) void qkv_gemm_kernel(
    const unsigned short* __restrict__ xb,
    const unsigned short* __restrict__ wqb, const unsigned short* __restrict__ wkb,
    const unsigned short* __restrict__ wvb,
    const float* __restrict__ bq, const float* __restrict__ bk, const float* __restrict__ bv,
    const float2* __restrict__ tab,
    unsigned short* __restrict__ Qr, unsigned short* __restrict__ Kr,
    unsigned short* __restrict__ VT)
{
    __shared__ __align__(16) unsigned short As[128 * 32];
    __shared__ __align__(16) unsigned short Bs[128 * 32];

    const int which = blockIdx.x >> 3;
    const int bn = (blockIdx.x & 7) * 128;
    const int bm = blockIdx.y * 128;
    const unsigned short* W = (which == 0) ? wqb : (which == 1) ? wkb : wvb;
    const float* bias       = (which == 0) ? bq  : (which == 1) ? bk  : bv;

    const int tid  = threadIdx.x;
    const int lane = tid & 63;
    const int w    = tid >> 6;
    const int quad = lane >> 4;
    const int l16  = lane & 15;
    const int wm   = (w >> 1) * 64;
    const int wn   = (w & 1) * 64;

    f32x4 acc[4][4];
#pragma unroll
    for (int i = 0; i < 4; ++i)
#pragma unroll
        for (int j = 0; j < 4; ++j)
            acc[i][j] = f32x4{0.f, 0.f, 0.f, 0.f};

    const int r0 = tid >> 2, c0 = (tid & 3) * 8;
    const unsigned short* ga0 = xb + (size_t)(bm + r0) * DMODEL + c0;
    const unsigned short* ga1 = ga0 + (size_t)64 * DMODEL;
    const unsigned short* gb0 = W  + (size_t)(bn + r0) * DMODEL + c0;
    const unsigned short* gb1 = gb0 + (size_t)64 * DMODEL;
    unsigned short* la0 = As + tid * 8;
    unsigned short* la1 = As + (tid + 256) * 8;
    unsigned short* lb0 = Bs + tid * 8;
    unsigned short* lb1 = Bs + (tid + 256) * 8;

    for (int k0 = 0; k0 < DMODEL; k0 += 32) {
        glds16(ga0 + k0, la0);
        glds16(ga1 + k0, la1);
        glds16(gb0 + k0, lb0);
        glds16(gb1 + k0, lb1);
        __syncthreads();

        bf16x8 aF[4], bF[4];
#pragma unroll
        for (int t = 0; t < 4; ++t) {
            aF[t] = *(const bf16x8*)(&As[(wm + t * 16 + l16) * 32 + quad * 8]);
            bF[t] = *(const bf16x8*)(&Bs[(wn + t * 16 + l16) * 32 + quad * 8]);
        }
#pragma unroll
        for (int mt = 0; mt < 4; ++mt)
#pragma unroll
            for (int nt = 0; nt < 4; ++nt)
                acc[mt][nt] = __builtin_amdgcn_mfma_f32_16x16x32_bf16(
                    aF[mt], bF[nt], acc[mt][nt], 0, 0, 0);
        __syncthreads();
    }

    // ---- epilogue
    if (which < 2) {
        unsigned short* Y = (which == 0) ? Qr : Kr;
        const float qscale = (which == 0) ? SCALE2 : 1.0f;
#pragma unroll
        for (int mt = 0; mt < 4; ++mt) {
            const int row0 = bm + wm + mt * 16 + quad * 4;
#pragma unroll
            for (int nt = 0; nt < 2; ++nt) {
                const int d   = nt * 16 + l16;       // 0..31 within head
                const int col = bn + wn + nt * 16 + l16;
                const float b1 = bias[col];
                const float b2 = bias[col + 32];
#pragma unroll
                for (int r = 0; r < 4; ++r) {
                    const int row = row0 + r;
                    const int s = row & (S_LEN - 1);
                    const float2 cs = tab[s * 32 + d];
                    const float x1 = acc[mt][nt][r] + b1;
                    const float x2 = acc[mt][nt + 2][r] + b2;
                    Y[(size_t)row * DMODEL + col]      = f2bf((x1 * cs.x - x2 * cs.y) * qscale);
                    Y[(size_t)row * DMODEL + col + 32] = f2bf((x2 * cs.x + x1 * cs.y) * qscale);
                }
            }
        }
    } else {
#pragma unroll
        for (int mt = 0; mt < 4; ++mt) {
            const int row0 = bm + wm + mt * 16 + quad * 4;
            const int bb = row0 >> 11, s0 = row0 & (S_LEN - 1);
            const int h = (bn + wn) >> 6;
#pragma unroll
            for (int nt = 0; nt < 4; ++nt) {
                const int d = nt * 16 + l16;
                const float bv2 = bias[bn + wn + nt * 16 + l16];
                unsigned short pk[4];
#pragma unroll
                for (int r = 0; r < 4; ++r)
                    pk[r] = f2bf(acc[mt][nt][r] + bv2);
                *(uint2*)(&VT[((size_t)(bb * NHEAD + h) * DHEAD + d) * S_LEN + s0]) =
                    *(const uint2*)pk;
            }
        }
    }
}

// ---------------------------------------------------------------- attention
// Round-13: revert to round-11 inner loop (verified, no partials), plus:
//  (a) pair-uniform blocks: block handles q-tiles (15-m) then (m) for one
//      (b,h) -> exactly 17 k-tile stages per block, 256 blocks, zero tail.
//  (b) double-buffered K/V staging with counted vmcnt (T3/T4): stage t+1's
//      4 glds/thread issued before compute(t); barrier A waits vmcnt(4)
//      (oldest 4 = tile t) so next-tile loads stay in flight across the
//      barrier; barrier B (lgkmcnt 0) protects buf reuse. Raw s_barrier --
//      __syncthreads would drain vmcnt(0) and defeat the prefetch.
// Rationale (rocprof r2): k-split partials cost 90 MB traffic (WRITE 8->80MB)
// and slowed attn; occupancy was a proxy for exposed stage latency, which
// (a)+(b) remove directly at zero extra traffic.
#define VSTR 136   // Pb row stride (shorts): 128 + 8 pad
#define NSTG 17    // (16-m) + (m+1) stages per block

__global__ __launch_bounds__(512) void attn_kernel(
    const unsigned short* __restrict__ Q, const unsigned short* __restrict__ K,
    const unsigned short* __restrict__ VT, unsigned short* __restrict__ O)
{
    const int j   = blockIdx.x;       // 0..255
    const int bh  = j >> 3;
    const int m   = j & 7;            // pair (15-m, m)
    const int b   = bh >> 4, h = bh & 15;
    const int qtA = 15 - m;           // heavy q-tile, stages 0..nA-1
    const int nA  = qtA + 1;          // 9..16

    const int tid  = threadIdx.x;
    const int w    = tid >> 6;        // 0..7
    const int lane = tid & 63;
    const int quad = lane >> 4;
    const int l16  = lane & 15;

    __shared__ __align__(16) unsigned short Ks[2][128 * 64];   // [kpos][dh]  swizzled
    __shared__ __align__(16) unsigned short Vt[2][64 * 128];   // [dh][kpos] swizzled
    __shared__ __align__(16) unsigned short Pb[8 * 16 * VSTR]; // per-wave [q][kpos]

    const unsigned short* Qb = Q  + (size_t)b * S_LEN * DMODEL + h * DHEAD;
    const unsigned short* Kb = K  + (size_t)b * S_LEN * DMODEL + h * DHEAD;
    const unsigned short* Vh = VT + ((size_t)(b * NHEAD + h)) * DHEAD * S_LEN;

    // Q fragments for both q-tiles (named scalars: no runtime-indexed reg arrays)
    const int rA = qtA * 128 + w * 16 + l16;
    const int rB = m   * 128 + w * 16 + l16;
    const bf16x8 qfA0 = *(const bf16x8*)(Qb + (size_t)rA * DMODEL + quad * 8);
    const bf16x8 qfA1 = *(const bf16x8*)(Qb + (size_t)rA * DMODEL + 32 + quad * 8);
    const bf16x8 qfB0 = *(const bf16x8*)(Qb + (size_t)rB * DMODEL + quad * 8);
    const bf16x8 qfB1 = *(const bf16x8*)(Qb + (size_t)rB * DMODEL + 32 + quad * 8);

    f32x4 o[4];
#pragma unroll
    for (int i = 0; i < 4; ++i) o[i] = f32x4{0.f, 0.f, 0.f, 0.f};
    float l_i[4] = {0.f, 0.f, 0.f, 0.f};

    unsigned short* Pw = &Pb[w * 16 * VSTR];

    // stage issue: 4 glds/thread (2 K + 2 V) for k-tile kt into buffer bs
#define STAGE(bs, kt_) do {                                                        \
        _Pragma("unroll")                                                          \
        for (int i_ = 0; i_ < 2; ++i_) {                                           \
            const int ck = tid + i_ * 512;                                         \
            const int krow = ck >> 3, kc = ck & 7;                                 \
            glds16(Kb + (size_t)((kt_) * 128 + krow) * DMODEL + ((kc ^ (krow & 7)) * 8), \
                   &Ks[bs][ck * 8]);                                               \
            const int vrow = ck >> 4, vc = ck & 15;                                \
            glds16(Vh + (size_t)vrow * S_LEN + (kt_) * 128 + ((vc ^ (vrow & 15)) * 8), \
                   &Vt[bs][ck * 8]);                                               \
        }                                                                          \
    } while (0)

    STAGE(0, 0);   // prologue: stage st=0 (kt=0 of qtA)

    for (int st = 0; st < NSTG; ++st) {
        const int cur = st & 1;

        // issue next stage into the other buffer, then wait only for current
        if (st + 1 < NSTG) {
            const int kt2 = (st + 1 < nA) ? (st + 1) : (st + 1 - nA);
            STAGE(cur ^ 1, kt2);
            if (st == nA) {
                // qtA epilogue's 16 stores sit between counted loads:
                // outstanding = [4 stage(st), 16 stores, 4 stage(st+1)];
                // in-order retirement -> vmcnt(20) proves stage(st) done.
                asm volatile("s_waitcnt vmcnt(20)" ::: "memory");
            } else {
                asm volatile("s_waitcnt vmcnt(4)" ::: "memory");
            }
        } else {
            asm volatile("s_waitcnt vmcnt(0)" ::: "memory");
        }
        __builtin_amdgcn_s_barrier();   // barrier A: buf[cur] ready for all waves

        const int inA = (st < nA) ? 1 : 0;
        const int qt  = inA ? qtA : m;
        const int kt  = inA ? st : st - nA;
        const bf16x8 qv0 = inA ? qfA0 : qfB0;
        const bf16x8 qv1 = inA ? qfA1 : qfB1;

        const bool diag = (kt == qt);
        // Wave w's rows only see kpos <= qt*128 + w*16 + 15 on the diagonal;
        // round up to a 32-kpos block so masked entries are exact zeros.
        const int ntmax = diag ? ((w & ~1) + 2) : 8;
        const int cmax  = ntmax >> 1;

        // ---- scores: 16 q-rows x (ntmax*16) kpos
        f32x4 sc[8];
#pragma unroll
        for (int nt = 0; nt < 8; ++nt) {
            if (nt >= ntmax) break;
            const int row = nt * 16 + l16;
            const bf16x8 kf0 = *(const bf16x8*)(&Ks[cur][row * 64 + ((quad ^ (l16 & 7)) * 8)]);
            const bf16x8 kf1 = *(const bf16x8*)(&Ks[cur][row * 64 + (((4 + quad) ^ (l16 & 7)) * 8)]);
            f32x4 a = f32x4{0.f, 0.f, 0.f, 0.f};
            a = __builtin_amdgcn_mfma_f32_16x16x32_bf16(qv0, kf0, a, 0, 0, 0);
            a = __builtin_amdgcn_mfma_f32_16x16x32_bf16(qv1, kf1, a, 0, 0, 0);
            sc[nt] = a;
        }

        if (diag) {   // triangular mask within the diagonal tile
            const int qpos0 = qt * 128 + w * 16 + quad * 4;
#pragma unroll
            for (int nt = 0; nt < 8; ++nt) {
                if (nt >= ntmax) break;
                const int kpos = kt * 128 + nt * 16 + l16;
#pragma unroll
                for (int r = 0; r < 4; ++r)
                    if (kpos > qpos0 + r) sc[nt][r] = -INFINITY;
            }
        }

        // ---- exp2 + unnormalized accumulate
#pragma unroll
        for (int nt = 0; nt < 8; ++nt) {
            if (nt >= ntmax) break;
#pragma unroll
            for (int r = 0; r < 4; ++r) {
                const float e = exp2f(sc[nt][r]);
                sc[nt][r] = e;
                l_i[r] += e;
            }
        }

        // ---- P: C-layout -> per-wave LDS -> A-layout (no barrier)
#pragma unroll
        for (int nt = 0; nt < 8; ++nt) {
            if (nt >= ntmax) break;
#pragma unroll
            for (int r = 0; r < 4; ++r)
                Pw[(quad * 4 + r) * VSTR + nt * 16 + l16] = f2bf(sc[nt][r]);
        }

        bf16x8 pA[4];
#pragma unroll
        for (int c = 0; c < 4; ++c) {
            if (c >= cmax) break;
            pA[c] = *(const bf16x8*)(&Pw[l16 * VSTR + c * 32 + quad * 8]);
        }
#pragma unroll
        for (int nt = 0; nt < 4; ++nt) {
            const int row = nt * 16 + l16;
#pragma unroll
            for (int c = 0; c < 4; ++c) {
                if (c >= cmax) break;
                const bf16x8 vF = *(const bf16x8*)(&Vt[cur][row * 128 + (((c * 4 + quad) ^ l16) * 8)]);
                o[nt] = __builtin_amdgcn_mfma_f32_16x16x32_bf16(pA[c], vF, o[nt], 0, 0, 0);
            }
        }

        asm volatile("s_waitcnt lgkmcnt(0)" ::: "memory");
        __builtin_amdgcn_s_barrier();   // barrier B: buf[cur] reads done everywhere

        if (st == nA - 1) {
            // ---- epilogue for q-tile A, then reset accumulators
            float linv[4];
#pragma unroll
            for (int r = 0; r < 4; ++r) {
                float rs = l_i[r];
#pragma unroll
                for (int msk = 1; msk < 16; msk <<= 1)
                    rs += __shfl_xor(rs, msk);
                linv[r] = 1.0f / rs;
            }
            const int spos0 = qtA * 128 + w * 16 + quad * 4;
#pragma unroll
            for (int nt = 0; nt < 4; ++nt)
#pragma unroll
                for (int r = 0; r < 4; ++r) {
                    const float val = o[nt][r] * linv[r];
                    O[((size_t)b * S_LEN + spos0 + r) * DMODEL + h * DHEAD + nt * 16 + l16] = f2bf(val);
                }
#pragma unroll
            for (int i = 0; i < 4; ++i) o[i] = f32x4{0.f, 0.f, 0.f, 0.f};
#pragma unroll
            for (int r = 0; r < 4; ++r) l_i[r] = 0.f;
        }
    }
#undef STAGE

    // ---- epilogue for q-tile B
    {
        float linv[4];
#pragma unroll
        for (int r = 0; r < 4; ++r) {
            float rs = l_i[r];
#pragma unroll
            for (int msk = 1; msk < 16; msk <<= 1)
                rs += __shfl_xor(rs, msk);
            linv[r] = 1.0f / rs;
        }
        const int spos0 = m * 128 + w * 16 + quad * 4;
#pragma unroll
        for (int nt = 0; nt < 4; ++nt)
#pragma unroll
            for (int r = 0; r < 4; ++r) {
                const float val = o[nt][r] * linv[r];
                O[((size_t)b * S_LEN + spos0 + r) * DMODEL + h * DHEAD + nt * 16 + l16] = f2bf(val);
            }
    }
}

// ---------------------------------------------------------------- out-proj GEMM (bf16 x bf16 -> fp32)
__global__ __launch_bounds__(256, 2) void outproj_kernel(
    const unsigned short* __restrict__ A, const unsigned short* __restrict__ W,
    const float* __restrict__ bias, float* __restrict__ C)
{
    __shared__ __align__(16) unsigned short As[64 * 32];
    __shared__ __align__(16) unsigned short Bs[128 * 32];

    const int tid  = threadIdx.x;
    const int lane = tid & 63;
    const int w    = tid >> 6;
    const int quad = lane >> 4;
    const int l16  = lane & 15;
    const int wm   = (w >> 1) * 32;
    const int wn   = (w & 1) * 64;
    const int bm   = blockIdx.y * 64;
    const int bn   = blockIdx.x * 128;

    f32x4 acc[2][4];
#pragma unroll
    for (int i = 0; i < 2; ++i)
#pragma unroll
        for (int j = 0; j < 4; ++j)
            acc[i][j] = f32x4{0.f, 0.f, 0.f, 0.f};

    const int r0 = tid >> 2, c0 = (tid & 3) * 8;
    const unsigned short* ga  = A + (size_t)(bm + r0) * DMODEL + c0;
    const unsigned short* gb0 = W + (size_t)(bn + r0) * DMODEL + c0;
    const unsigned short* gb1 = gb0 + (size_t)64 * DMODEL;
    unsigned short* la  = As + tid * 8;
    unsigned short* lb0 = Bs + tid * 8;
    unsigned short* lb1 = Bs + (tid + 256) * 8;

    for (int k0 = 0; k0 < DMODEL; k0 += 32) {
        glds16(ga + k0, la);
        glds16(gb0 + k0, lb0);
        glds16(gb1 + k0, lb1);
        __syncthreads();

        bf16x8 aF[2], bF[4];
#pragma unroll
        for (int t = 0; t < 2; ++t)
            aF[t] = *(const bf16x8*)(&As[(wm + t * 16 + l16) * 32 + quad * 8]);
#pragma unroll
        for (int t = 0; t < 4; ++t)
            bF[t] = *(const bf16x8*)(&Bs[(wn + t * 16 + l16) * 32 + quad * 8]);
#pragma unroll
        for (int mt = 0; mt < 2; ++mt)
#pragma unroll
            for (int nt = 0; nt < 4; ++nt)
                acc[mt][nt] = __builtin_amdgcn_mfma_f32_16x16x32_bf16(
                    aF[mt], bF[nt], acc[mt][nt], 0, 0, 0);
        __syncthreads();
    }

#pragma unroll
    for (int mt = 0; mt < 2; ++mt) {
        const int row0 = bm + wm + mt * 16 + quad * 4;
#pragma unroll
        for (int nt = 0; nt < 4; ++nt) {
            const int col = bn + wn + nt * 16 + l16;
            const float bv = bias[col];
#pragma unroll
            for (int r = 0; r < 4; ++r)
                C[(size_t)(row0 + r) * DMODEL + col] = acc[mt][nt][r] + bv;
        }
    }
}

// ---------------------------------------------------------------- launch
extern "C" void kernel_launch(void* const* d_in, const int* in_sizes, int n_in,
                              void* d_out, int out_size, void* d_ws, size_t ws_size,
                              hipStream_t stream) {
    const float* x  = (const float*)d_in[0];
    const float* Wq = (const float*)d_in[1];
    const float* bq = (const float*)d_in[2];
    const float* Wk = (const float*)d_in[3];
    const float* bk = (const float*)d_in[4];
    const float* Wv = (const float*)d_in[5];
    const float* bv = (const float*)d_in[6];
    const float* Wo = (const float*)d_in[7];
    const float* bo = (const float*)d_in[8];
    float* out = (float*)d_out;

    char* ws = (char*)d_ws;
    const size_t MB = 1 << 20;
    unsigned short* xb  = (unsigned short*)(ws);            //  8 MB
    unsigned short* wqb = (unsigned short*)(ws + 8  * MB);  //  2 MB each
    unsigned short* wkb = (unsigned short*)(ws + 10 * MB);
    unsigned short* wvb = (unsigned short*)(ws + 12 * MB);
    unsigned short* wob = (unsigned short*)(ws + 14 * MB);
    float2*         tab = (float2*)       (ws + 16 * MB);   // 512 KB
    unsigned short* Qr  = (unsigned short*)(ws + 17 * MB);  //  8 MB
    unsigned short* Kr  = (unsigned short*)(ws + 25 * MB);
    unsigned short* VT  = (unsigned short*)(ws + 33 * MB);
    unsigned short* AO  = (unsigned short*)(ws + 41 * MB);

    const int M = BATCH * S_LEN;   // 4096

    cvt_kernel<<<dim3(4096, 5), 256, 0, stream>>>(
        x, Wq, Wk, Wv, Wo, xb, wqb, wkb, wvb, wob);

    rope_table_kernel<<<256, 256, 0, stream>>>(tab);

    qkv_gemm_kernel<<<dim3(24, M / 128), 256, 0, stream>>>(
        xb, wqb, wkb, wvb, bq, bk, bv, tab, Qr, Kr, VT);

    attn_kernel<<<dim3(256), 512, 0, stream>>>(Qr, Kr, VT, AO);

    outproj_kernel<<<dim3(DMODEL / 128, M / 64), 256, 0, stream>>>(AO, wob, bo, out);
}

// Round 4
// 196.606 us; speedup vs baseline: 1.1557x; 1.0486x over previous
//
#include <hip/hip_runtime.h>
#include <math.h>

// ---------------------------------------------------------------- types
typedef __bf16 bf16_t;
typedef bf16_t bf16x8 __attribute__((ext_vector_type(8)));
typedef float f32x4 __attribute__((ext_vector_type(4)));
typedef unsigned int u32x4 __attribute__((ext_vector_type(4)));

#define S_LEN 2048
#define NHEAD 16
#define DHEAD 64
#define DMODEL 1024
#define BATCH 2

__device__ __forceinline__ float bf2f(unsigned short u) {
    unsigned int x = ((unsigned int)u) << 16;
    return __builtin_bit_cast(float, x);
}
__device__ __forceinline__ unsigned short f2bf(float f) {
    unsigned int x = __builtin_bit_cast(unsigned int, f);
    x += 0x7fffu + ((x >> 16) & 1u);          // RNE
    return (unsigned short)(x >> 16);
}

// async global->LDS, 16B per lane. LDS dest = wave-uniform base + lane*16.
__device__ __forceinline__ void glds16(const void* g, void* l) {
    __builtin_amdgcn_global_load_lds(
        (__attribute__((address_space(1))) void*)g,
        (__attribute__((address_space(3))) void*)l,
        16, 0, 0);
}

#define SCALE2 0.1803368801f   // 1/sqrt(64) * log2(e), folded into Q at qkv epilogue

// ---------------------------------------------------------------- fp32 -> bf16 convert
__global__ __launch_bounds__(256) void cvt_kernel(
    const float* __restrict__ x,  const float* __restrict__ wq,
    const float* __restrict__ wk, const float* __restrict__ wv,
    const float* __restrict__ wo,
    unsigned short* __restrict__ xb,  unsigned short* __restrict__ wqb,
    unsigned short* __restrict__ wkb, unsigned short* __restrict__ wvb,
    unsigned short* __restrict__ wob)
{
    const int y = blockIdx.y;
    const float* s = (y == 0) ? x : (y == 1) ? wq : (y == 2) ? wk : (y == 3) ? wv : wo;
    unsigned short* d = (y == 0) ? xb : (y == 1) ? wqb : (y == 2) ? wkb : (y == 3) ? wvb : wob;
    const int n4 = (y == 0) ? (1 << 20) : (1 << 18);
    const int i = blockIdx.x * 256 + threadIdx.x;
    if (i < n4) {
        float4 v = ((const float4*)s)[i];
        ushort4 o;
        o.x = f2bf(v.x); o.y = f2bf(v.y); o.z = f2bf(v.z); o.w = f2bf(v.w);
        ((ushort4*)d)[i] = o;
    }
}

// ---------------------------------------------------------------- RoPE cos/sin table
__global__ __launch_bounds__(256) void rope_table_kernel(float2* __restrict__ tab)
{
    const int gid = blockIdx.x * 256 + threadIdx.x;   // 65536
    const int s = gid >> 5, d = gid & 31;
    const float freq = exp2f(-0.4152410119f * (float)d);
    const float ang = (float)s * freq;
    tab[gid] = make_float2(cosf(ang), sinf(ang));
}

// ---------------------------------------------------------------- fused QKV GEMM
__global__ __launch_bounds__(256, 2) void qkv_gemm_kernel(
    const unsigned short* __restrict__ xb,
    const unsigned short* __restrict__ wqb, const unsigned short* __restrict__ wkb,
    const unsigned short* __restrict__ wvb,
    const float* __restrict__ bq, const float* __restrict__ bk, const float* __restrict__ bv,
    const float2* __restrict__ tab,
    unsigned short* __restrict__ Qr, unsigned short* __restrict__ Kr,
    unsigned short* __restrict__ VT)
{
    __shared__ __align__(16) unsigned short As[128 * 32];
    __shared__ __align__(16) unsigned short Bs[128 * 32];

    const int which = blockIdx.x >> 3;
    const int bn = (blockIdx.x & 7) * 128;
    const int bm = blockIdx.y * 128;
    const unsigned short* W = (which == 0) ? wqb : (which == 1) ? wkb : wvb;
    const float* bias       = (which == 0) ? bq  : (which == 1) ? bk  : bv;

    const int tid  = threadIdx.x;
    const int lane = tid & 63;
    const int w    = tid >> 6;
    const int quad = lane >> 4;
    const int l16  = lane & 15;
    const int wm   = (w >> 1) * 64;
    const int wn   = (w & 1) * 64;

    f32x4 acc[4][4];
#pragma unroll
    for (int i = 0; i < 4; ++i)
#pragma unroll
        for (int j = 0; j < 4; ++j)
            acc[i][j] = f32x4{0.f, 0.f, 0.f, 0.f};

    const int r0 = tid >> 2, c0 = (tid & 3) * 8;
    const unsigned short* ga0 = xb + (size_t)(bm + r0) * DMODEL + c0;
    const unsigned short* ga1 = ga0 + (size_t)64 * DMODEL;
    const unsigned short* gb0 = W  + (size_t)(bn + r0) * DMODEL + c0;
    const unsigned short* gb1 = gb0 + (size_t)64 * DMODEL;
    unsigned short* la0 = As + tid * 8;
    unsigned short* la1 = As + (tid + 256) * 8;
    unsigned short* lb0 = Bs + tid * 8;
    unsigned short* lb1 = Bs + (tid + 256) * 8;

    for (int k0 = 0; k0 < DMODEL; k0 += 32) {
        glds16(ga0 + k0, la0);
        glds16(ga1 + k0, la1);
        glds16(gb0 + k0, lb0);
        glds16(gb1 + k0, lb1);
        __syncthreads();

        bf16x8 aF[4], bF[4];
#pragma unroll
        for (int t = 0; t < 4; ++t) {
            aF[t] = *(const bf16x8*)(&As[(wm + t * 16 + l16) * 32 + quad * 8]);
            bF[t] = *(const bf16x8*)(&Bs[(wn + t * 16 + l16) * 32 + quad * 8]);
        }
#pragma unroll
        for (int mt = 0; mt < 4; ++mt)
#pragma unroll
            for (int nt = 0; nt < 4; ++nt)
                acc[mt][nt] = __builtin_amdgcn_mfma_f32_16x16x32_bf16(
                    aF[mt], bF[nt], acc[mt][nt], 0, 0, 0);
        __syncthreads();
    }

    // ---- epilogue
    if (which < 2) {
        unsigned short* Y = (which == 0) ? Qr : Kr;
        const float qscale = (which == 0) ? SCALE2 : 1.0f;
#pragma unroll
        for (int mt = 0; mt < 4; ++mt) {
            const int row0 = bm + wm + mt * 16 + quad * 4;
#pragma unroll
            for (int nt = 0; nt < 2; ++nt) {
                const int d   = nt * 16 + l16;       // 0..31 within head
                const int col = bn + wn + nt * 16 + l16;
                const float b1 = bias[col];
                const float b2 = bias[col + 32];
#pragma unroll
                for (int r = 0; r < 4; ++r) {
                    const int row = row0 + r;
                    const int s = row & (S_LEN - 1);
                    const float2 cs = tab[s * 32 + d];
                    const float x1 = acc[mt][nt][r] + b1;
                    const float x2 = acc[mt][nt + 2][r] + b2;
                    Y[(size_t)row * DMODEL + col]      = f2bf((x1 * cs.x - x2 * cs.y) * qscale);
                    Y[(size_t)row * DMODEL + col + 32] = f2bf((x2 * cs.x + x1 * cs.y) * qscale);
                }
            }
        }
    } else {
#pragma unroll
        for (int mt = 0; mt < 4; ++mt) {
            const int row0 = bm + wm + mt * 16 + quad * 4;
            const int bb = row0 >> 11, s0 = row0 & (S_LEN - 1);
            const int h = (bn + wn) >> 6;
#pragma unroll
            for (int nt = 0; nt < 4; ++nt) {
                const int d = nt * 16 + l16;
                const float bv2 = bias[bn + wn + nt * 16 + l16];
                unsigned short pk[4];
#pragma unroll
                for (int r = 0; r < 4; ++r)
                    pk[r] = f2bf(acc[mt][nt][r] + bv2);
                *(uint2*)(&VT[((size_t)(bb * NHEAD + h) * DHEAD + d) * S_LEN + s0]) =
                    *(const uint2*)pk;
            }
        }
    }
}

// ---------------------------------------------------------------- attention
// Round-14: in-register P via swapped QK^T.
//  - mfma(kf, qf) instead of mfma(qf, kf): A/B fragments of 16x16x32 have
//    IDENTICAL lane maps (16-dim=l16, k=quad*8+j), so the swap needs no
//    operand relayout. Output S^T: lane holds q=l16, kpos=nt*16+quad*4+r.
//  - P never touches LDS: v_cvt_pk_bf16_f32 packs pairs; 6 shfl_xor
//    (16/32/48) + selects redistribute k across quads into the PV A-frag.
//    Pb (34.8 KB) deleted -> LDS = dbuf K/V = 64 KB -> 2 blocks/CU WITH
//    double-buffered counted-vmcnt staging (r3's pipeline, r1's occupancy).
//  - grid: 512 blocks, j = qs*32 + bh: j%8 = bh%8 (same-(b,h) on one XCD,
//    K/V 4MB = L2-resident); CU-pairs (j, j+256) have qt complementary
//    (15-qs, qs-8) -> 17 stages per CU, heavy tiles dispatch first.
__global__ __launch_bounds__(512, 4) void attn_kernel(
    const unsigned short* __restrict__ Q, const unsigned short* __restrict__ K,
    const unsigned short* __restrict__ VT, unsigned short* __restrict__ O)
{
    const int j  = blockIdx.x;          // 0..511
    const int bh = j & 31;
    const int qs = j >> 5;              // 0..15
    const int b  = bh >> 4, h = bh & 15;
    const int qt = (qs < 8) ? (15 - qs) : (qs - 8);

    const int tid  = threadIdx.x;
    const int w    = tid >> 6;          // 0..7
    const int lane = tid & 63;
    const int quad = lane >> 4;
    const int l16  = lane & 15;

    __shared__ __align__(16) unsigned short Ks[2][128 * 64];   // [kpos][dh]  swizzled
    __shared__ __align__(16) unsigned short Vt[2][64 * 128];   // [dh][kpos] swizzled

    const int q0 = qt * 128;
    const unsigned short* Qb = Q  + (size_t)b * S_LEN * DMODEL + h * DHEAD;
    const unsigned short* Kb = K  + (size_t)b * S_LEN * DMODEL + h * DHEAD;
    const unsigned short* Vh = VT + ((size_t)(b * NHEAD + h)) * DHEAD * S_LEN;

    // Q fragment (B-operand of swapped QK^T): rows q0 + w*16 + l16
    const int qrow = q0 + w * 16 + l16;
    const bf16x8 qf0 = *(const bf16x8*)(Qb + (size_t)qrow * DMODEL + quad * 8);
    const bf16x8 qf1 = *(const bf16x8*)(Qb + (size_t)qrow * DMODEL + 32 + quad * 8);

    f32x4 o[4];
#pragma unroll
    for (int i = 0; i < 4; ++i) o[i] = f32x4{0.f, 0.f, 0.f, 0.f};
    float l_acc = 0.f;

    const int nkt = qt + 1;

#define STAGE(bs, kt_) do {                                                        \
        _Pragma("unroll")                                                          \
        for (int i_ = 0; i_ < 2; ++i_) {                                           \
            const int ck = tid + i_ * 512;                                         \
            const int krow = ck >> 3, kc = ck & 7;                                 \
            glds16(Kb + (size_t)((kt_) * 128 + krow) * DMODEL + ((kc ^ (krow & 7)) * 8), \
                   &Ks[bs][ck * 8]);                                               \
            const int vrow = ck >> 4, vc = ck & 15;                                \
            glds16(Vh + (size_t)vrow * S_LEN + (kt_) * 128 + ((vc ^ (vrow & 15)) * 8), \
                   &Vt[bs][ck * 8]);                                               \
        }                                                                          \
    } while (0)

    STAGE(0, 0);

    for (int kt = 0; kt < nkt; ++kt) {
        const int cur = kt & 1;

        if (kt + 1 < nkt) {
            STAGE(cur ^ 1, kt + 1);
            asm volatile("s_waitcnt vmcnt(4)" ::: "memory");
        } else {
            asm volatile("s_waitcnt vmcnt(0)" ::: "memory");
        }
        __builtin_amdgcn_s_barrier();   // barrier A: buf[cur] staged for all waves

        const bool diag = (kt == qt);
        const int ntmax = diag ? ((w & ~1) + 2) : 8;
        const int cmax  = ntmax >> 1;

        // ---- scores (swapped): sc[nt] = S^T fragment, lane: q=l16,
        //      kpos = kt*128 + nt*16 + quad*4 + r
        f32x4 sc[8];
#pragma unroll
        for (int nt = 0; nt < 8; ++nt) {
            if (nt >= ntmax) break;
            const int row = nt * 16 + l16;
            const bf16x8 kf0 = *(const bf16x8*)(&Ks[cur][row * 64 + ((quad ^ (l16 & 7)) * 8)]);
            const bf16x8 kf1 = *(const bf16x8*)(&Ks[cur][row * 64 + (((4 + quad) ^ (l16 & 7)) * 8)]);
            f32x4 a = f32x4{0.f, 0.f, 0.f, 0.f};
            a = __builtin_amdgcn_mfma_f32_16x16x32_bf16(kf0, qf0, a, 0, 0, 0);
            a = __builtin_amdgcn_mfma_f32_16x16x32_bf16(kf1, qf1, a, 0, 0, 0);
            sc[nt] = a;
        }

        if (diag) {   // mask kpos > qpos;  kpos-thr = nt*16 + r
            const int thr = q0 + w * 16 + l16 - kt * 128 - quad * 4;
#pragma unroll
            for (int nt = 0; nt < 8; ++nt) {
                if (nt >= ntmax) break;
#pragma unroll
                for (int r = 0; r < 4; ++r)
                    if (nt * 16 + r > thr) sc[nt][r] = -INFINITY;
            }
        }

        // ---- exp2 + row-sum (lane owns one q-row: scalar accumulator)
#pragma unroll
        for (int nt = 0; nt < 8; ++nt) {
            if (nt >= ntmax) break;
#pragma unroll
            for (int r = 0; r < 4; ++r) {
                const float e = exp2f(sc[nt][r]);
                sc[nt][r] = e;
                l_acc += e;
            }
        }

        // ---- P -> PV A-frags, all in registers (no LDS round-trip).
        // source words: quad holds k-words {8nt+2quad, 8nt+2quad+1};
        // dest quad Q needs words {16c+4Q..+3}: Q0:[m0,m1,X0,X1]
        // Q1:[B0,B1,A0,A1] Q2:[A0,A1,B0,B1] Q3:[X0,X1,m0,m1]
        bf16x8 pA[4];
        const bool qlo = (quad < 2);
#pragma unroll
        for (int c = 0; c < 4; ++c) {
            if (c >= cmax) break;
            unsigned int s0, s1, t0, t1;
            asm("v_cvt_pk_bf16_f32 %0, %1, %2" : "=v"(s0) : "v"(sc[2*c][0]),   "v"(sc[2*c][1]));
            asm("v_cvt_pk_bf16_f32 %0, %1, %2" : "=v"(s1) : "v"(sc[2*c][2]),   "v"(sc[2*c][3]));
            asm("v_cvt_pk_bf16_f32 %0, %1, %2" : "=v"(t0) : "v"(sc[2*c+1][0]), "v"(sc[2*c+1][1]));
            asm("v_cvt_pk_bf16_f32 %0, %1, %2" : "=v"(t1) : "v"(sc[2*c+1][2]), "v"(sc[2*c+1][3]));
            const unsigned int m0 = qlo ? s0 : t0, m1 = qlo ? s1 : t1;
            const unsigned int n0 = qlo ? t0 : s0, n1 = qlo ? t1 : s1;
            const unsigned int X0 = __shfl_xor(m0, 16), X1 = __shfl_xor(m1, 16);
            const unsigned int A0 = __shfl_xor(n0, 32), A1 = __shfl_xor(n1, 32);
            const unsigned int B0 = __shfl_xor(n0, 48), B1 = __shfl_xor(n1, 48);
            u32x4 aw;
            aw[0] = qlo ? (quad == 0 ? m0 : B0) : (quad == 2 ? A0 : X0);
            aw[1] = qlo ? (quad == 0 ? m1 : B1) : (quad == 2 ? A1 : X1);
            aw[2] = qlo ? (quad == 0 ? X0 : A0) : (quad == 2 ? B0 : m0);
            aw[3] = qlo ? (quad == 0 ? X1 : A1) : (quad == 2 ? B1 : m1);
            pA[c] = __builtin_bit_cast(bf16x8, aw);
        }

#pragma unroll
        for (int nt = 0; nt < 4; ++nt) {
            const int row = nt * 16 + l16;
#pragma unroll
            for (int c = 0; c < 4; ++c) {
                if (c >= cmax) break;
                const bf16x8 vF = *(const bf16x8*)(&Vt[cur][row * 128 + (((c * 4 + quad) ^ l16) * 8)]);
                o[nt] = __builtin_amdgcn_mfma_f32_16x16x32_bf16(pA[c], vF, o[nt], 0, 0, 0);
            }
        }

        asm volatile("s_waitcnt lgkmcnt(0)" ::: "memory");
        __builtin_amdgcn_s_barrier();   // barrier B: buf[cur] reads done everywhere
    }
#undef STAGE

    // ---- epilogue: full row-sum = reduce over quads; redistribute to o-rows
    {
        float rs = l_acc;
        rs += __shfl_xor(rs, 16);
        rs += __shfl_xor(rs, 32);       // full sum for q = l16, uniform over quads
        const float linv_row = 1.0f / rs;
        float linv[4];
#pragma unroll
        for (int r = 0; r < 4; ++r)
            linv[r] = __shfl(linv_row, quad * 4 + r);   // l for q = quad*4+r

        const int spos0 = q0 + w * 16 + quad * 4;
#pragma unroll
        for (int nt = 0; nt < 4; ++nt)
#pragma unroll
            for (int r = 0; r < 4; ++r) {
                const float val = o[nt][r] * linv[r];
                O[((size_t)b * S_LEN + spos0 + r) * DMODEL + h * DHEAD + nt * 16 + l16] = f2bf(val);
            }
    }
}

// ---------------------------------------------------------------- out-proj GEMM (bf16 x bf16 -> fp32)
__global__ __launch_bounds__(256, 2) void outproj_kernel(
    const unsigned short* __restrict__ A, const unsigned short* __restrict__ W,
    const float* __restrict__ bias, float* __restrict__ C)
{
    __shared__ __align__(16) unsigned short As[64 * 32];
    __shared__ __align__(16) unsigned short Bs[128 * 32];

    const int tid  = threadIdx.x;
    const int lane = tid & 63;
    const int w    = tid >> 6;
    const int quad = lane >> 4;
    const int l16  = lane & 15;
    const int wm   = (w >> 1) * 32;
    const int wn   = (w & 1) * 64;
    const int bm   = blockIdx.y * 64;
    const int bn   = blockIdx.x * 128;

    f32x4 acc[2][4];
#pragma unroll
    for (int i = 0; i < 2; ++i)
#pragma unroll
        for (int j = 0; j < 4; ++j)
            acc[i][j] = f32x4{0.f, 0.f, 0.f, 0.f};

    const int r0 = tid >> 2, c0 = (tid & 3) * 8;
    const unsigned short* ga  = A + (size_t)(bm + r0) * DMODEL + c0;
    const unsigned short* gb0 = W + (size_t)(bn + r0) * DMODEL + c0;
    const unsigned short* gb1 = gb0 + (size_t)64 * DMODEL;
    unsigned short* la  = As + tid * 8;
    unsigned short* lb0 = Bs + tid * 8;
    unsigned short* lb1 = Bs + (tid + 256) * 8;

    for (int k0 = 0; k0 < DMODEL; k0 += 32) {
        glds16(ga + k0, la);
        glds16(gb0 + k0, lb0);
        glds16(gb1 + k0, lb1);
        __syncthreads();

        bf16x8 aF[2], bF[4];
#pragma unroll
        for (int t = 0; t < 2; ++t)
            aF[t] = *(const bf16x8*)(&As[(wm + t * 16 + l16) * 32 + quad * 8]);
#pragma unroll
        for (int t = 0; t < 4; ++t)
            bF[t] = *(const bf16x8*)(&Bs[(wn + t * 16 + l16) * 32 + quad * 8]);
#pragma unroll
        for (int mt = 0; mt < 2; ++mt)
#pragma unroll
            for (int nt = 0; nt < 4; ++nt)
                acc[mt][nt] = __builtin_amdgcn_mfma_f32_16x16x32_bf16(
                    aF[mt], bF[nt], acc[mt][nt], 0, 0, 0);
        __syncthreads();
    }

#pragma unroll
    for (int mt = 0; mt < 2; ++mt) {
        const int row0 = bm + wm + mt * 16 + quad * 4;
#pragma unroll
        for (int nt = 0; nt < 4; ++nt) {
            const int col = bn + wn + nt * 16 + l16;
            const float bv = bias[col];
#pragma unroll
            for (int r = 0; r < 4; ++r)
                C[(size_t)(row0 + r) * DMODEL + col] = acc[mt][nt][r] + bv;
        }
    }
}

// ---------------------------------------------------------------- launch
extern "C" void kernel_launch(void* const* d_in, const int* in_sizes, int n_in,
                              void* d_out, int out_size, void* d_ws, size_t ws_size,
                              hipStream_t stream) {
    const float* x  = (const float*)d_in[0];
    const float* Wq = (const float*)d_in[1];
    const float* bq = (const float*)d_in[2];
    const float* Wk = (const float*)d_in[3];
    const float* bk = (const float*)d_in[4];
    const float* Wv = (const float*)d_in[5];
    const float* bv = (const float*)d_in[6];
    const float* Wo = (const float*)d_in[7];
    const float* bo = (const float*)d_in[8];
    float* out = (float*)d_out;

    char* ws = (char*)d_ws;
    const size_t MB = 1 << 20;
    unsigned short* xb  = (unsigned short*)(ws);            //  8 MB
    unsigned short* wqb = (unsigned short*)(ws + 8  * MB);  //  2 MB each
    unsigned short* wkb = (unsigned short*)(ws + 10 * MB);
    unsigned short* wvb = (unsigned short*)(ws + 12 * MB);
    unsigned short* wob = (unsigned short*)(ws + 14 * MB);
    float2*         tab = (float2*)       (ws + 16 * MB);   // 512 KB
    unsigned short* Qr  = (unsigned short*)(ws + 17 * MB);  //  8 MB
    unsigned short* Kr  = (unsigned short*)(ws + 25 * MB);
    unsigned short* VT  = (unsigned short*)(ws + 33 * MB);
    unsigned short* AO  = (unsigned short*)(ws + 41 * MB);

    const int M = BATCH * S_LEN;   // 4096

    cvt_kernel<<<dim3(4096, 5), 256, 0, stream>>>(
        x, Wq, Wk, Wv, Wo, xb, wqb, wkb, wvb, wob);

    rope_table_kernel<<<256, 256, 0, stream>>>(tab);

    qkv_gemm_kernel<<<dim3(24, M / 128), 256, 0, stream>>>(
        xb, wqb, wkb, wvb, bq, bk, bv, tab, Qr, Kr, VT);

    attn_kernel<<<dim3(512), 512, 0, stream>>>(Qr, Kr, VT, AO);

    outproj_kernel<<<dim3(DMODEL / 128, M / 64), 256, 0, stream>>>(AO, wob, bo, out);
}